// Round 14
// baseline (185.174 us; speedup 1.0000x reference)
//
#include <hip/hip_runtime.h>
#include <math.h>

#define CT    320
#define NPTS  1024
#define DFEAT 256
#define DPOS  64
#define KSEL  32

// ============ Kernel C: per-point 1/max(||pos||,eps) -> rnjg (ws) ===========
__global__ void gnn_rnj(const float* __restrict__ in, float* __restrict__ rnjg) {
  const int b     = blockIdx.x;
  const int batch = b >> 2;
  const int j     = ((b & 3) << 8) + threadIdx.x;
  const float* __restrict__ pbase = in + (size_t)batch * CT * NPTS + (size_t)DFEAT * NPTS;
  float s = 0.f;
#pragma unroll 8
  for (int d = 0; d < DPOS; ++d) {
    const float x = pbase[(size_t)d * NPTS + j];
    s = fmaf(x, x, s);
  }
  rnjg[batch * NPTS + j] = 1.0f / fmaxf(sqrtf(s), 1e-12f);
}

// ================= Kernel A: sim + exact top-32 + softmax -> pairs(ws) ======
// Round-11 configuration verbatim (best measured: 64 us). 1024 blocks; 16
// rows/blk; wave owns 4 full rows; triple-buffered jt with counted vmcnt(2);
// 15-bit float-threshold exact top-32.
#define AROWS 16
#define DCH   2                         // d-rows per staged chunk
#define QSTEP 6.103515625e-05f          // 2^-14, thr(m) = m*QSTEP - 1 (exact)
__global__ __launch_bounds__(256, 4) void gnn_sim_topk(const float* __restrict__ in,
                                                       const float* __restrict__ rnjg,
                                                       float2* __restrict__ pairs) {
  __shared__ float pi[DPOS * 20];      // [d][i], stride 20 (16B-aligned quads)
  __shared__ float rnjL[NPTS];
  __shared__ float jt[3][DCH * 1024];  // staged j-chunks (8 KB each), 3-deep
  __shared__ float cand[AROWS][68];    // 32 interleaved (v,j) pairs + pad

  const int p     = blockIdx.x;
  const int batch = ((p & 7) << 1) | ((p >> 3) & 1);   // 2 batches per XCD
  const int chunk = p >> 4;            // 0..63
  const int i0    = chunk * AROWS;
  const int tid   = threadIdx.x;
  const int w     = tid >> 6;
  const int lane  = tid & 63;

  const float* __restrict__ pbase = in + (size_t)batch * CT * NPTS + (size_t)DFEAT * NPTS;

  // stage raw pos of the 16 rows
  {
    const int i = tid & 15;
    const int d0 = tid >> 4;           // 0..15
#pragma unroll
    for (int pass = 0; pass < 4; ++pass) {
      const int d = pass * 16 + d0;
      pi[d * 20 + i] = pbase[(size_t)d * NPTS + i0 + i];
    }
  }
  // rnj table for this batch (4 KB, one float4 per thread)
  *(float4*)&rnjL[tid * 4] = *(const float4*)&rnjg[batch * NPTS + tid * 4];

  // j-chunk stage: wave w -> d-row (w>>1), half (w&1); 2 x 16B-wide async
#define JSTAGE(buf, c)                                                           \
  do {                                                                           \
    const int dd_   = (w >> 1);                                                  \
    const int half_ = (w & 1);                                                   \
    const float* src_ = pbase + (size_t)((c) * DCH + dd_) * NPTS + half_ * 512 + lane * 4; \
    float* dst_ = &jt[buf][dd_ * 1024 + half_ * 512];                            \
    __builtin_amdgcn_global_load_lds(                                            \
        (const __attribute__((address_space(1))) void*)(src_),                   \
        (__attribute__((address_space(3))) void*)(dst_), 16, 0, 0);              \
    __builtin_amdgcn_global_load_lds(                                            \
        (const __attribute__((address_space(1))) void*)(src_ + 256),             \
        (__attribute__((address_space(3))) void*)(dst_ + 256), 16, 0, 0);        \
  } while (0)

  JSTAGE(0, 0);
  JSTAGE(1, 1);
  asm volatile("s_waitcnt vmcnt(2)" ::: "memory");   // chunk 0 landed; 1 in flight
  __syncthreads();                     // pi, rnjL, jt[0] ready

  // ---- sim: wave w owns rows w*4..w*4+3; lane owns j = u*256 + lane*4 + t ----
  float acc[4][16];
#pragma unroll
  for (int r = 0; r < 4; ++r)
#pragma unroll
    for (int s = 0; s < 16; ++s) acc[r][s] = 0.f;

  int cur = 0;
  for (int c = 0; c < DPOS / DCH; ++c) {
#pragma unroll
    for (int dd = 0; dd < DCH; ++dd) {
      const int d = c * DCH + dd;
      const float4 pv4 = *(const float4*)&pi[d * 20 + w * 4];   // broadcast
      const float pr_[4] = {pv4.x, pv4.y, pv4.z, pv4.w};
      float4 jv[4];
#pragma unroll
      for (int u = 0; u < 4; ++u)
        jv[u] = *(const float4*)&jt[cur][dd * 1024 + u * 256 + lane * 4];
#pragma unroll
      for (int r = 0; r < 4; ++r) {
#pragma unroll
        for (int u = 0; u < 4; ++u) {
          acc[r][u*4+0] = fmaf(pr_[r], jv[u].x, acc[r][u*4+0]);
          acc[r][u*4+1] = fmaf(pr_[r], jv[u].y, acc[r][u*4+1]);
          acc[r][u*4+2] = fmaf(pr_[r], jv[u].z, acc[r][u*4+2]);
          acc[r][u*4+3] = fmaf(pr_[r], jv[u].w, acc[r][u*4+3]);
        }
      }
    }
    // stage 2 ahead; counted wait: next chunk landed, newest still in flight
    if (c < DPOS / DCH - 2) {
      const int nbuf = (cur + 2 >= 3) ? cur - 1 : cur + 2;
      JSTAGE(nbuf, c + 2);
      asm volatile("s_waitcnt vmcnt(2)" ::: "memory");
    } else {
      asm volatile("s_waitcnt vmcnt(0)" ::: "memory");
    }
    __syncthreads();                   // readers of overwritten buf are >=1 BAR back
    cur = (cur + 1 >= 3) ? 0 : cur + 1;
  }
#undef JSTAGE

  // per-lane rnj for its 16 j slots
  float4 rv[4];
#pragma unroll
  for (int u = 0; u < 4; ++u) rv[u] = *(const float4*)&rnjL[u * 256 + lane * 4];

  // ---- per-row exact top-32 + softmax, straight from registers ----
#pragma unroll
  for (int r = 0; r < 4; ++r) {
    const int rglob = w * 4 + r;
    const float sc = rnjL[i0 + rglob];         // rni == rnj of the row's point
    float v[16];
#pragma unroll
    for (int u = 0; u < 4; ++u) {
      v[u*4+0] = acc[r][u*4+0] * rv[u].x * sc;
      v[u*4+1] = acc[r][u*4+1] * rv[u].y * sc;
      v[u*4+2] = acc[r][u*4+2] * rv[u].z * sc;
      v[u*4+3] = acc[r][u*4+3] * rv[u].w * sc;
    }
    // 15-bit float-threshold search: largest lo with count(v >= thr(lo)) >= 32
    int lo = 0;
#pragma unroll
    for (int bit = 16384; bit >= 1; bit >>= 1) {
      const float thrf = (float)(lo + bit) * QSTEP - 1.0f;
      int cnt = 0;
#pragma unroll
      for (int t = 0; t < 16; ++t) cnt += (int)__popcll(__ballot(v[t] >= thrf));
      if (cnt >= KSEL) lo += bit;
    }
    const float thr_h = (float)(lo + 1) * QSTEP - 1.0f;   // definite threshold
    const float thr_l = (float)lo * QSTEP - 1.0f;         // boundary low edge
    // compact definite members (v >= thr_h); boundary bin -> cmask
    int cbase = 0;
    unsigned cmask = 0u;
#pragma unroll
    for (int t = 0; t < 16; ++t) {
      const bool hi = (v[t] >= thr_h);
      const unsigned long long m = __ballot(hi);
      if (hi) {
        const int pos = cbase + (int)__builtin_amdgcn_mbcnt_hi(
            (unsigned)(m >> 32), __builtin_amdgcn_mbcnt_lo((unsigned)m, 0u));
        const int j = (t >> 2) * 256 + lane * 4 + (t & 3);
        *(float2*)&cand[rglob][2 * pos] = make_float2(v[t], __int_as_float(j));
      }
      cbase += (int)__popcll(m);
      if ((v[t] >= thr_l) && !hi) cmask |= (1u << t);
    }
    // boundary: exact (v desc, j asc); at 2^-14 bins this runs ~1 iteration
    const int need = KSEL - cbase;
    for (int it = 0; it < need; ++it) {
      float bv = -2.0f; int bj = 0x7fffffff; int bt = 16;
#pragma unroll
      for (int t = 0; t < 16; ++t) {
        if (((cmask >> t) & 1u) && v[t] > bv) {
          bv = v[t]; bj = (t >> 2) * 256 + lane * 4 + (t & 3); bt = t;
        }
      }
      float rvv = bv; int rj = bj;
#pragma unroll
      for (int s = 1; s < 64; s <<= 1) {
        const float ov = __shfl_xor(rvv, s);
        const int   oj = __shfl_xor(rj, s);
        if (ov > rvv || (ov == rvv && oj < rj)) { rvv = ov; rj = oj; }
      }
      if (bv == rvv && bj == rj) {             // unique winner (j unique)
        *(float2*)&cand[rglob][2 * (cbase + it)] = make_float2(bv, __int_as_float(bj));
        cmask &= ~(1u << bt);
      }
    }
    // softmax over the selected 32 (order-invariant)
    {
      const float x = cand[rglob][2 * (lane & 31)];
      float mx = x;
#pragma unroll
      for (int s = 16; s >= 1; s >>= 1) mx = fmaxf(mx, __shfl_xor(mx, s));
      const float e = expf(x - mx);
      float sum = e;
#pragma unroll
      for (int s = 16; s >= 1; s >>= 1) sum += __shfl_xor(sum, s);
      if (lane < KSEL) cand[rglob][2 * lane] = e / sum;
    }
  }
  __syncthreads();

  // write (attn, id) pairs, coalesced float4 (2 pairs per thread)
  {
    const int pidx = tid * 2;            // pair index
    const int r = pidx >> 5, k = pidx & 31;
    const float4 o4 = *(const float4*)&cand[r][2 * k];
    *(float4*)&pairs[((size_t)batch * NPTS + i0 + r) * KSEL + k] = o4;
  }
}

// ================= Kernel B: gather, loop-inverted (round-14 fix) ===========
// 512 blocks x 256 threads; block owns 8 CHANNELS x all 1024 rows of a batch.
// Feat staged ONCE per block; no barriers in main loop. Row r's 32 pairs =
// 16 float4 at pb4[r*16 + q]  (round-13 bug: used stride 8, q<8 -> half the
// k-terms dropped, absmax 1.27).
__global__ __launch_bounds__(256, 2) void gnn_gather(const float* __restrict__ in,
                                                     const float2* __restrict__ pairs,
                                                     float* __restrict__ out) {
  __shared__ float fst[8 * 1028];      // this block's 8 channel-rows (32.9 KB)

  const int p     = blockIdx.x;
  const int batch = ((p & 7) << 1) | ((p >> 3) & 1);   // 2 batches per XCD
  const int cg    = p >> 4;            // channel group 0..31
  const int tid   = threadIdx.x;
  const int w     = tid >> 6;
  const int lane  = tid & 63;

  const float* __restrict__ fbase = in + (size_t)batch * CT * NPTS;

  // stage the 8 channel-rows once: wave w -> rows {2w, 2w+1}
#pragma unroll
  for (int rr = 0; rr < 2; ++rr) {
    const int crow = w * 2 + rr;
    const float* src = fbase + (size_t)(cg * 8 + crow) * NPTS + lane * 4;
    float* dst = &fst[crow * 1028];
#pragma unroll
    for (int qq = 0; qq < 4; ++qq)
      __builtin_amdgcn_global_load_lds(
          (const __attribute__((address_space(1))) void*)(src + qq * 256),
          (__attribute__((address_space(3))) void*)(dst + qq * 256), 16, 0, 0);
  }

  const int c     = lane >> 3;         // channel slot 0..7
  const int rl    = lane & 7;
  const int rbase = w * 8 + rl;        // row within 32-row tile
  const float* fb = &fst[c * 1028];
  const float4* pb4 = (const float4*)(pairs + (size_t)batch * NPTS * KSEL);
  float* const obase = out + ((size_t)batch * DFEAT + cg * 8 + c) * NPTS;

  asm volatile("s_waitcnt vmcnt(0)" ::: "memory");   // fst landed
  __syncthreads();                                   // barrier-free after this

  for (int t = 0; t < 32; ++t) {
    const int row = t * 32 + rbase;
    // row's 32 (attn, id) pairs = 16 float4 (8 lanes share row -> L2 coalesce)
    float4 cp[16];
#pragma unroll
    for (int q = 0; q < 16; ++q) cp[q] = pb4[(size_t)row * 16 + q];
    float o = 0.f;
#pragma unroll
    for (int q = 0; q < 16; ++q) {     // k ascending: bitwise-same sum order
      o = fmaf(cp[q].x, fb[__float_as_int(cp[q].y)], o);
      o = fmaf(cp[q].z, fb[__float_as_int(cp[q].w)], o);
    }
    obase[row] = o;
  }
}

extern "C" void kernel_launch(void* const* d_in, const int* in_sizes, int n_in,
                              void* d_out, int out_size, void* d_ws, size_t ws_size,
                              hipStream_t stream) {
  const float* in = (const float*)d_in[0];
  float* out = (float*)d_out;
  float2* pairs = (float2*)d_ws;                           // 4 MB
  float*  rnjg  = (float*)((char*)d_ws + (16u << 20) / 4); // +4 MB: 64 KB table
  gnn_rnj<<<dim3(64), dim3(256), 0, stream>>>(in, rnjg);
  gnn_sim_topk<<<dim3(1024), dim3(256), 0, stream>>>(in, rnjg, pairs);
  gnn_gather<<<dim3(512), dim3(256), 0, stream>>>(in, pairs, out);
}

// Round 17
// 124.554 us; speedup vs baseline: 1.4867x; 1.4867x over previous
//
#include <hip/hip_runtime.h>
#include <math.h>

#define CT    320
#define NPTS  1024
#define DFEAT 256
#define DPOS  64
#define KSEL  32

// ============ Kernel C: per-point 1/max(||pos||,eps) -> rnjg (ws) ===========
__global__ void gnn_rnj(const float* __restrict__ in, float* __restrict__ rnjg) {
  const int b     = blockIdx.x;
  const int batch = b >> 2;
  const int j     = ((b & 3) << 8) + threadIdx.x;
  const float* __restrict__ pbase = in + (size_t)batch * CT * NPTS + (size_t)DFEAT * NPTS;
  float s = 0.f;
#pragma unroll 8
  for (int d = 0; d < DPOS; ++d) {
    const float x = pbase[(size_t)d * NPTS + j];
    s = fmaf(x, x, s);
  }
  rnjg[batch * NPTS + j] = 1.0f / fmaxf(sqrtf(s), 1e-12f);
}

// ================= Kernel A: sim + exact top-32 + softmax -> pairs(ws) ======
// Round-15 config (third submission; two infra failures, never measured).
// Wave owns 8 FULL rows (acc[8][16], AROWS=32, 512 blocks): FMA:LDS = 128:4
// per d -> LDS-read pressure halves vs 4-rows/wave; sim becomes VALU-bound.
// bounds(256,2) = 256-VGPR budget (live ~170). Topk: 15-bit float-threshold.
#define AROWS 32
#define DCH   2                         // d-rows per staged chunk
#define QSTEP 6.103515625e-05f          // 2^-14, thr(m) = m*QSTEP - 1 (exact)
__global__ __launch_bounds__(256, 2) void gnn_sim_topk(const float* __restrict__ in,
                                                       const float* __restrict__ rnjg,
                                                       float2* __restrict__ pairs) {
  __shared__ float pi[DPOS * 36];      // [d][i], 32 rows padded to 36
  __shared__ float rnjL[NPTS];
  __shared__ float jt[3][DCH * 1024];  // staged j-chunks (8 KB each), 3-deep
  __shared__ float cand[AROWS][68];    // 32 interleaved (v,j) pairs + pad

  const int p     = blockIdx.x;
  const int batch = ((p & 7) << 1) | ((p >> 3) & 1);   // 2 batches per XCD
  const int chunk = p >> 4;            // 0..31
  const int i0    = chunk * AROWS;
  const int tid   = threadIdx.x;
  const int w     = tid >> 6;
  const int lane  = tid & 63;

  const float* __restrict__ pbase = in + (size_t)batch * CT * NPTS + (size_t)DFEAT * NPTS;

  // stage raw pos of the 32 rows: thread t -> (i = t&31, d = pass*8 + t>>5)
  {
    const int i  = tid & 31;
    const int d0 = tid >> 5;           // 0..7
#pragma unroll
    for (int pass = 0; pass < 8; ++pass) {
      const int d = pass * 8 + d0;
      pi[d * 36 + i] = pbase[(size_t)d * NPTS + i0 + i];
    }
  }
  // rnj table for this batch (4 KB, one float4 per thread)
  *(float4*)&rnjL[tid * 4] = *(const float4*)&rnjg[batch * NPTS + tid * 4];

  // j-chunk stage: wave w -> d-row (w>>1), half (w&1); 2 x 16B-wide async
#define JSTAGE(buf, c)                                                           \
  do {                                                                           \
    const int dd_   = (w >> 1);                                                  \
    const int half_ = (w & 1);                                                   \
    const float* src_ = pbase + (size_t)((c) * DCH + dd_) * NPTS + half_ * 512 + lane * 4; \
    float* dst_ = &jt[buf][dd_ * 1024 + half_ * 512];                            \
    __builtin_amdgcn_global_load_lds(                                            \
        (const __attribute__((address_space(1))) void*)(src_),                   \
        (__attribute__((address_space(3))) void*)(dst_), 16, 0, 0);              \
    __builtin_amdgcn_global_load_lds(                                            \
        (const __attribute__((address_space(1))) void*)(src_ + 256),             \
        (__attribute__((address_space(3))) void*)(dst_ + 256), 16, 0, 0);        \
  } while (0)

  JSTAGE(0, 0);
  JSTAGE(1, 1);
  asm volatile("s_waitcnt vmcnt(2)" ::: "memory");   // chunk 0 landed; 1 in flight
  __syncthreads();                     // pi, rnjL, jt[0] ready

  // ---- sim: wave w owns rows w*8..w*8+7; lane owns j = u*256 + lane*4 + t ----
  float acc[8][16];
#pragma unroll
  for (int r = 0; r < 8; ++r)
#pragma unroll
    for (int s = 0; s < 16; ++s) acc[r][s] = 0.f;

  int cur = 0;
  for (int c = 0; c < DPOS / DCH; ++c) {
#pragma unroll
    for (int dd = 0; dd < DCH; ++dd) {
      const int d = c * DCH + dd;
      const float4 pva = *(const float4*)&pi[d * 36 + w * 8];     // broadcast
      const float4 pvb = *(const float4*)&pi[d * 36 + w * 8 + 4];
      const float pr_[8] = {pva.x, pva.y, pva.z, pva.w, pvb.x, pvb.y, pvb.z, pvb.w};
      float4 jv[4];
#pragma unroll
      for (int u = 0; u < 4; ++u)
        jv[u] = *(const float4*)&jt[cur][dd * 1024 + u * 256 + lane * 4];
#pragma unroll
      for (int r = 0; r < 8; ++r) {
#pragma unroll
        for (int u = 0; u < 4; ++u) {
          acc[r][u*4+0] = fmaf(pr_[r], jv[u].x, acc[r][u*4+0]);
          acc[r][u*4+1] = fmaf(pr_[r], jv[u].y, acc[r][u*4+1]);
          acc[r][u*4+2] = fmaf(pr_[r], jv[u].z, acc[r][u*4+2]);
          acc[r][u*4+3] = fmaf(pr_[r], jv[u].w, acc[r][u*4+3]);
        }
      }
    }
    // stage 2 ahead; counted wait: next chunk landed, newest still in flight
    if (c < DPOS / DCH - 2) {
      const int nbuf = (cur + 2 >= 3) ? cur - 1 : cur + 2;
      JSTAGE(nbuf, c + 2);
      asm volatile("s_waitcnt vmcnt(2)" ::: "memory");
    } else {
      asm volatile("s_waitcnt vmcnt(0)" ::: "memory");
    }
    __syncthreads();                   // readers of overwritten buf are >=1 BAR back
    cur = (cur + 1 >= 3) ? 0 : cur + 1;
  }
#undef JSTAGE

  // per-lane rnj for its 16 j slots
  float4 rv[4];
#pragma unroll
  for (int u = 0; u < 4; ++u) rv[u] = *(const float4*)&rnjL[u * 256 + lane * 4];

  // ---- per-row exact top-32 + softmax, straight from registers ----
#pragma unroll
  for (int r = 0; r < 8; ++r) {
    const int rglob = w * 8 + r;
    const float sc = rnjL[i0 + rglob];         // rni == rnj of the row's point
    float v[16];
#pragma unroll
    for (int u = 0; u < 4; ++u) {
      v[u*4+0] = acc[r][u*4+0] * rv[u].x * sc;
      v[u*4+1] = acc[r][u*4+1] * rv[u].y * sc;
      v[u*4+2] = acc[r][u*4+2] * rv[u].z * sc;
      v[u*4+3] = acc[r][u*4+3] * rv[u].w * sc;
    }
    // 15-bit float-threshold search: largest lo with count(v >= thr(lo)) >= 32
    int lo = 0;
#pragma unroll
    for (int bit = 16384; bit >= 1; bit >>= 1) {
      const float thrf = (float)(lo + bit) * QSTEP - 1.0f;
      int cnt = 0;
#pragma unroll
      for (int t = 0; t < 16; ++t) cnt += (int)__popcll(__ballot(v[t] >= thrf));
      if (cnt >= KSEL) lo += bit;
    }
    const float thr_h = (float)(lo + 1) * QSTEP - 1.0f;   // definite threshold
    const float thr_l = (float)lo * QSTEP - 1.0f;         // boundary low edge
    // compact definite members (v >= thr_h); boundary bin -> cmask
    int cbase = 0;
    unsigned cmask = 0u;
#pragma unroll
    for (int t = 0; t < 16; ++t) {
      const bool hi = (v[t] >= thr_h);
      const unsigned long long m = __ballot(hi);
      if (hi) {
        const int pos = cbase + (int)__builtin_amdgcn_mbcnt_hi(
            (unsigned)(m >> 32), __builtin_amdgcn_mbcnt_lo((unsigned)m, 0u));
        const int j = (t >> 2) * 256 + lane * 4 + (t & 3);
        *(float2*)&cand[rglob][2 * pos] = make_float2(v[t], __int_as_float(j));
      }
      cbase += (int)__popcll(m);
      if ((v[t] >= thr_l) && !hi) cmask |= (1u << t);
    }
    // boundary: exact (v desc, j asc); at 2^-14 bins this runs ~1 iteration
    const int need = KSEL - cbase;
    for (int it = 0; it < need; ++it) {
      float bv = -2.0f; int bj = 0x7fffffff; int bt = 16;
#pragma unroll
      for (int t = 0; t < 16; ++t) {
        if (((cmask >> t) & 1u) && v[t] > bv) {
          bv = v[t]; bj = (t >> 2) * 256 + lane * 4 + (t & 3); bt = t;
        }
      }
      float rvv = bv; int rj = bj;
#pragma unroll
      for (int s = 1; s < 64; s <<= 1) {
        const float ov = __shfl_xor(rvv, s);
        const int   oj = __shfl_xor(rj, s);
        if (ov > rvv || (ov == rvv && oj < rj)) { rvv = ov; rj = oj; }
      }
      if (bv == rvv && bj == rj) {             // unique winner (j unique)
        *(float2*)&cand[rglob][2 * (cbase + it)] = make_float2(bv, __int_as_float(bj));
        cmask &= ~(1u << bt);
      }
    }
    // softmax over the selected 32 (order-invariant)
    {
      const float x = cand[rglob][2 * (lane & 31)];
      float mx = x;
#pragma unroll
      for (int s = 16; s >= 1; s >>= 1) mx = fmaxf(mx, __shfl_xor(mx, s));
      const float e = expf(x - mx);
      float sum = e;
#pragma unroll
      for (int s = 16; s >= 1; s >>= 1) sum += __shfl_xor(sum, s);
      if (lane < KSEL) cand[rglob][2 * lane] = e / sum;
    }
  }
  __syncthreads();

  // write (attn, id) pairs: 1024 pairs = 512 float4, 2 per thread
#pragma unroll
  for (int h = 0; h < 2; ++h) {
    const int pidx = h * 512 + tid * 2;  // pair index
    const int r = pidx >> 5, k = pidx & 31;
    const float4 o4 = *(const float4*)&cand[r][2 * k];
    *(float4*)&pairs[((size_t)batch * NPTS + i0 + r) * KSEL + k] = o4;
  }
}

// ================= Kernel B: gather (round-12 proven version) ===============
// 512 blocks x 256 threads; 32 rows/block; thread owns row, pairs in regs;
// feat staged 8 channels/pass, double-buffered global_load_lds.
__global__ __launch_bounds__(256, 2) void gnn_gather(const float* __restrict__ in,
                                                     const float2* __restrict__ pairs,
                                                     float* __restrict__ out) {
  __shared__ float fst[2][8 * 1028];   // 8 channel-rows per cc pass
  __shared__ float pr[32 * 68];        // [row][34 pairs]: a at 2k, j-bits at 2k+1

  const int p     = blockIdx.x;
  const int batch = ((p & 7) << 1) | ((p >> 3) & 1);
  const int chunk = p >> 4;            // 0..31
  const int i0    = chunk * 32;
  const int tid   = threadIdx.x;
  const int w     = tid >> 6;
  const int lane  = tid & 63;

  const float* __restrict__ fbase = in + (size_t)batch * CT * NPTS;

  // pairs -> LDS (1024 pairs = 512 float4)
  {
    const float4* pb4 = (const float4*)(pairs + ((size_t)batch * NPTS + i0) * KSEL);
#pragma unroll
    for (int h = 0; h < 2; ++h) {
      const int pidx = h * 256 + tid;          // float4 index: 2 pairs each
      const float4 q4 = pb4[pidx];
      const int r = pidx >> 4;                 // 16 float4 per row
      const int u = pidx & 15;
      *(float4*)&pr[r * 68 + u * 4] = q4;
    }
  }

  // stage helper: wave w stages channel-rows {2w, 2w+1} of pass cc into buf
#define STAGE(buf, ccv)                                                          \
  do {                                                                           \
    _Pragma("unroll")                                                            \
    for (int rr = 0; rr < 2; ++rr) {                                             \
      const int crow = w * 2 + rr;                                               \
      const float* src = fbase + (size_t)((ccv) * 8 + crow) * NPTS + lane * 4;   \
      float* dst = &fst[buf][crow * 1028];                                       \
      _Pragma("unroll")                                                          \
      for (int qq = 0; qq < 4; ++qq)                                             \
        __builtin_amdgcn_global_load_lds(                                        \
            (const __attribute__((address_space(1))) void*)(src + qq * 256),     \
            (__attribute__((address_space(3))) void*)(dst + qq * 256), 16, 0, 0);\
    }                                                                            \
  } while (0)

  STAGE(0, 0);
  asm volatile("s_waitcnt vmcnt(0)" ::: "memory");
  __syncthreads();

  const int c   = lane >> 3;           // channel slot 0..7
  const int rl  = lane & 7;
  const int row = w * 8 + rl;          // output row 0..31
  const float* prr = &pr[row * 68];

  for (int cc = 0; cc < 32; ++cc) {
    const int cur = cc & 1;
    if (cc < 31) STAGE(cur ^ 1, cc + 1);

    const float* fb = &fst[cur][c * 1028];
    float o = 0.f;
#pragma unroll
    for (int k = 0; k < KSEL; ++k) {
      const float2 pj = *(const float2*)&prr[2 * k];   // conflict-free broadcast
      o = fmaf(pj.x, fb[__float_as_int(pj.y)], o);     // 8 random j per instr
    }
    out[((size_t)batch * DFEAT + cc * 8 + c) * NPTS + i0 + row] = o;

    asm volatile("s_waitcnt vmcnt(0)" ::: "memory");
    __syncthreads();
  }
#undef STAGE
}

extern "C" void kernel_launch(void* const* d_in, const int* in_sizes, int n_in,
                              void* d_out, int out_size, void* d_ws, size_t ws_size,
                              hipStream_t stream) {
  const float* in = (const float*)d_in[0];
  float* out = (float*)d_out;
  float2* pairs = (float2*)d_ws;                           // 4 MB
  float*  rnjg  = (float*)((char*)d_ws + (16u << 20) / 4); // +4 MB: 64 KB table
  gnn_rnj<<<dim3(64), dim3(256), 0, stream>>>(in, rnjg);
  gnn_sim_topk<<<dim3(512), dim3(256), 0, stream>>>(in, rnjg, pairs);
  gnn_gather<<<dim3(512), dim3(256), 0, stream>>>(in, pairs, out);
}

// Round 18
// 114.772 us; speedup vs baseline: 1.6134x; 1.0852x over previous
//
#include <hip/hip_runtime.h>
#include <math.h>

#define CT    320
#define NPTS  1024
#define DFEAT 256
#define DPOS  64
#define KSEL  32

// ============ Kernel C: per-point 1/max(||pos||,eps) -> rnjg (ws) ===========
__global__ void gnn_rnj(const float* __restrict__ in, float* __restrict__ rnjg) {
  const int b     = blockIdx.x;
  const int batch = b >> 2;
  const int j     = ((b & 3) << 8) + threadIdx.x;
  const float* __restrict__ pbase = in + (size_t)batch * CT * NPTS + (size_t)DFEAT * NPTS;
  float s = 0.f;
#pragma unroll 8
  for (int d = 0; d < DPOS; ++d) {
    const float x = pbase[(size_t)d * NPTS + j];
    s = fmaf(x, x, s);
  }
  rnjg[batch * NPTS + j] = 1.0f / fmaxf(sqrtf(s), 1e-12f);
}

// ================= Kernel A: sim + exact top-32 + softmax -> pairs(ws) ======
// Round-18: strip layout, LDS-free sim. Wave owns j-strip [w*256,(w+1)*256),
// all 8 rows; lane owns 4 j. j loaded as ONE float4/d from L2 (no jt LDS, no
// JSTAGE, no sim barriers); row values pr_[8] are wave-uniform -> compiler
// emits s_load (SMEM pipe, no LDS, no VGPR). Sim is pure VALU ~14 us.
// Topk: per-strip partial top-32 -> cand LDS -> 128->32 merge (exact,
// float-threshold + (v desc, j asc) boundary; round-3/5-proven structure).
// acc[8][4]=32 VGPR -> no spill at bounds(256,4); grid 2048 = 2 exact passes.
#define AROWS 8
#define QSTEP 6.103515625e-05f          // 2^-14, thr(m) = m*QSTEP - 1 (exact)
__global__ __launch_bounds__(256, 4) void gnn_sim_topk(const float* __restrict__ in,
                                                       const float* __restrict__ rnjg,
                                                       float2* __restrict__ pairs) {
  __shared__ float cand[AROWS][260];   // 128 interleaved (v,j) pairs + pad

  const int p     = blockIdx.x;
  const int batch = ((p & 7) << 1) | ((p >> 3) & 1);   // same-batch -> same XCD
  const int chunk = p >> 4;            // 0..127
  const int i0    = chunk * AROWS;
  const int tid   = threadIdx.x;
  const int w     = tid >> 6;
  const int lane  = tid & 63;

  const float* __restrict__ pbase = in + (size_t)batch * CT * NPTS + (size_t)DFEAT * NPTS;

  // ---- sim: zero LDS, zero barriers ----
  float acc[AROWS][4];
#pragma unroll
  for (int r = 0; r < AROWS; ++r) { acc[r][0]=0.f; acc[r][1]=0.f; acc[r][2]=0.f; acc[r][3]=0.f; }

  const float* jp = pbase + w * 256 + lane * 4;
#pragma unroll 4
  for (int d = 0; d < DPOS; ++d) {
    // wave-uniform row values (no lane dependence -> scalar loads, SMEM pipe)
    const float* prow = pbase + (size_t)d * NPTS + i0;
    const float4 pa = *(const float4*)&prow[0];
    const float4 pb = *(const float4*)&prow[4];
    const float pr_[8] = {pa.x, pa.y, pa.z, pa.w, pb.x, pb.y, pb.z, pb.w};
    // per-lane j values: one float4 from L2
    const float4 jv = *(const float4*)(jp + (size_t)d * NPTS);
#pragma unroll
    for (int r = 0; r < AROWS; ++r) {
      acc[r][0] = fmaf(pr_[r], jv.x, acc[r][0]);
      acc[r][1] = fmaf(pr_[r], jv.y, acc[r][1]);
      acc[r][2] = fmaf(pr_[r], jv.z, acc[r][2]);
      acc[r][3] = fmaf(pr_[r], jv.w, acc[r][3]);
    }
  }

  // per-lane rnj for its 4 j slots (L2-hot 4 KB table); per-row sc is uniform
  const float4 rv4 = *(const float4*)&rnjg[(size_t)batch * NPTS + w * 256 + lane * 4];
  float scrow[AROWS];
  {
    const float4 sa = *(const float4*)&rnjg[(size_t)batch * NPTS + i0];
    const float4 sb = *(const float4*)&rnjg[(size_t)batch * NPTS + i0 + 4];
    scrow[0]=sa.x; scrow[1]=sa.y; scrow[2]=sa.z; scrow[3]=sa.w;
    scrow[4]=sb.x; scrow[5]=sb.y; scrow[6]=sb.z; scrow[7]=sb.w;
  }
  const int jbase = w * 256 + lane * 4;

  // ---- phase 1: per-strip exact top-32 -> cand[r][w*32 pairs] ----
#pragma unroll
  for (int r = 0; r < AROWS; ++r) {
    const float sc = scrow[r];
    float v[4];
    v[0] = acc[r][0] * rv4.x * sc;
    v[1] = acc[r][1] * rv4.y * sc;
    v[2] = acc[r][2] * rv4.z * sc;
    v[3] = acc[r][3] * rv4.w * sc;
    // largest lo with count(v >= thr(lo)) >= 32 within this 256-j strip
    int lo = 0;
#pragma unroll
    for (int bit = 16384; bit >= 1; bit >>= 1) {
      const float thrf = (float)(lo + bit) * QSTEP - 1.0f;
      int cnt = 0;
#pragma unroll
      for (int t = 0; t < 4; ++t) cnt += (int)__popcll(__ballot(v[t] >= thrf));
      if (cnt >= KSEL) lo += bit;
    }
    const float thr_h = (float)(lo + 1) * QSTEP - 1.0f;
    const float thr_l = (float)lo * QSTEP - 1.0f;
    int cbase = 0;
    unsigned cmask = 0u;
    float* const crow = &cand[r][2 * (w * KSEL)];
#pragma unroll
    for (int t = 0; t < 4; ++t) {
      const bool hi = (v[t] >= thr_h);
      const unsigned long long m = __ballot(hi);
      if (hi) {
        const int pos = cbase + (int)__builtin_amdgcn_mbcnt_hi(
            (unsigned)(m >> 32), __builtin_amdgcn_mbcnt_lo((unsigned)m, 0u));
        *(float2*)&crow[2 * pos] = make_float2(v[t], __int_as_float(jbase + t));
      }
      cbase += (int)__popcll(m);
      if ((v[t] >= thr_l) && !hi) cmask |= (1u << t);
    }
    const int need = KSEL - cbase;
    for (int it = 0; it < need; ++it) {
      float bv = -2.0f; int bj = 0x7fffffff; int bt = 4;
#pragma unroll
      for (int t = 0; t < 4; ++t) {
        if (((cmask >> t) & 1u) && v[t] > bv) { bv = v[t]; bj = jbase + t; bt = t; }
      }
      float rvv = bv; int rj = bj;
#pragma unroll
      for (int s = 1; s < 64; s <<= 1) {
        const float ov = __shfl_xor(rvv, s);
        const int   oj = __shfl_xor(rj, s);
        if (ov > rvv || (ov == rvv && oj < rj)) { rvv = ov; rj = oj; }
      }
      if (bv == rvv && bj == rj) {             // unique winner (j unique)
        *(float2*)&crow[2 * (cbase + it)] = make_float2(bv, __int_as_float(bj));
        cmask &= ~(1u << bt);
      }
    }
  }
  __syncthreads();

  // ---- phase 2: merge 128 candidates -> exact top-32 + softmax ----
#pragma unroll
  for (int rr = 0; rr < 2; ++rr) {
    const int r = w * 2 + rr;
    const float4 c4 = *(const float4*)&cand[r][lane * 4];   // 2 pairs per lane
    float v2[2] = { c4.x, c4.z };
    int   j2[2] = { __float_as_int(c4.y), __float_as_int(c4.w) };
    int lo = 0;
#pragma unroll
    for (int bit = 16384; bit >= 1; bit >>= 1) {
      const float thrf = (float)(lo + bit) * QSTEP - 1.0f;
      const int cnt = (int)__popcll(__ballot(v2[0] >= thrf)) +
                      (int)__popcll(__ballot(v2[1] >= thrf));
      if (cnt >= KSEL) lo += bit;
    }
    const float thr_h = (float)(lo + 1) * QSTEP - 1.0f;
    const float thr_l = (float)lo * QSTEP - 1.0f;
    int cbase = 0;
    unsigned cmask = 0u;
#pragma unroll
    for (int t = 0; t < 2; ++t) {
      const bool hi = (v2[t] >= thr_h);
      const unsigned long long m = __ballot(hi);
      if (hi) {
        const int pos = cbase + (int)__builtin_amdgcn_mbcnt_hi(
            (unsigned)(m >> 32), __builtin_amdgcn_mbcnt_lo((unsigned)m, 0u));
        *(float2*)&cand[r][2 * pos] = make_float2(v2[t], __int_as_float(j2[t]));
      }
      cbase += (int)__popcll(m);
      if ((v2[t] >= thr_l) && !hi) cmask |= (1u << t);
    }
    const int need = KSEL - cbase;
    for (int it = 0; it < need; ++it) {
      float bv = -2.0f; int bj = 0x7fffffff; int bt = 2;
#pragma unroll
      for (int t = 0; t < 2; ++t) {
        if (((cmask >> t) & 1u) && v2[t] > bv) { bv = v2[t]; bj = j2[t]; bt = t; }
      }
      float rvv = bv; int rj = bj;
#pragma unroll
      for (int s = 1; s < 64; s <<= 1) {
        const float ov = __shfl_xor(rvv, s);
        const int   oj = __shfl_xor(rj, s);
        if (ov > rvv || (ov == rvv && oj < rj)) { rvv = ov; rj = oj; }
      }
      if (bv == rvv && bj == rj) {
        *(float2*)&cand[r][2 * (cbase + it)] = make_float2(bv, __int_as_float(bj));
        cmask &= ~(1u << bt);
      }
    }
    // softmax over the selected 32 (order-invariant)
    {
      const float x = cand[r][2 * (lane & 31)];
      float mx = x;
#pragma unroll
      for (int s = 16; s >= 1; s >>= 1) mx = fmaxf(mx, __shfl_xor(mx, s));
      const float e = expf(x - mx);
      float sum = e;
#pragma unroll
      for (int s = 16; s >= 1; s >>= 1) sum += __shfl_xor(sum, s);
      if (lane < KSEL) cand[r][2 * lane] = e / sum;
    }
  }
  __syncthreads();

  // write (attn, id) pairs: 256 pairs = 128 float4
  if (tid < 128) {
    const int pidx = tid * 2;
    const int r = pidx >> 5, k = pidx & 31;
    const float4 o4 = *(const float4*)&cand[r][2 * k];
    *(float4*)&pairs[((size_t)batch * NPTS + i0 + r) * KSEL + k] = o4;
  }
}

// ================= Kernel B: gather (round-12 proven version) ===============
// 512 blocks x 256 threads; 32 rows/block; thread owns row, pairs in regs;
// feat staged 8 channels/pass, double-buffered global_load_lds.
__global__ __launch_bounds__(256, 2) void gnn_gather(const float* __restrict__ in,
                                                     const float2* __restrict__ pairs,
                                                     float* __restrict__ out) {
  __shared__ float fst[2][8 * 1028];   // 8 channel-rows per cc pass
  __shared__ float pr[32 * 68];        // [row][34 pairs]: a at 2k, j-bits at 2k+1

  const int p     = blockIdx.x;
  const int batch = ((p & 7) << 1) | ((p >> 3) & 1);
  const int chunk = p >> 4;            // 0..31
  const int i0    = chunk * 32;
  const int tid   = threadIdx.x;
  const int w     = tid >> 6;
  const int lane  = tid & 63;

  const float* __restrict__ fbase = in + (size_t)batch * CT * NPTS;

  // pairs -> LDS (1024 pairs = 512 float4)
  {
    const float4* pb4 = (const float4*)(pairs + ((size_t)batch * NPTS + i0) * KSEL);
#pragma unroll
    for (int h = 0; h < 2; ++h) {
      const int pidx = h * 256 + tid;          // float4 index: 2 pairs each
      const float4 q4 = pb4[pidx];
      const int r = pidx >> 4;                 // 16 float4 per row
      const int u = pidx & 15;
      *(float4*)&pr[r * 68 + u * 4] = q4;
    }
  }

  // stage helper: wave w stages channel-rows {2w, 2w+1} of pass cc into buf
#define STAGE(buf, ccv)                                                          \
  do {                                                                           \
    _Pragma("unroll")                                                            \
    for (int rr = 0; rr < 2; ++rr) {                                             \
      const int crow = w * 2 + rr;                                               \
      const float* src = fbase + (size_t)((ccv) * 8 + crow) * NPTS + lane * 4;   \
      float* dst = &fst[buf][crow * 1028];                                       \
      _Pragma("unroll")                                                          \
      for (int qq = 0; qq < 4; ++qq)                                             \
        __builtin_amdgcn_global_load_lds(                                        \
            (const __attribute__((address_space(1))) void*)(src + qq * 256),     \
            (__attribute__((address_space(3))) void*)(dst + qq * 256), 16, 0, 0);\
    }                                                                            \
  } while (0)

  STAGE(0, 0);
  asm volatile("s_waitcnt vmcnt(0)" ::: "memory");
  __syncthreads();

  const int c   = lane >> 3;           // channel slot 0..7
  const int rl  = lane & 7;
  const int row = w * 8 + rl;          // output row 0..31
  const float* prr = &pr[row * 68];

  for (int cc = 0; cc < 32; ++cc) {
    const int cur = cc & 1;
    if (cc < 31) STAGE(cur ^ 1, cc + 1);

    const float* fb = &fst[cur][c * 1028];
    float o = 0.f;
#pragma unroll
    for (int k = 0; k < KSEL; ++k) {
      const float2 pj = *(const float2*)&prr[2 * k];   // conflict-free broadcast
      o = fmaf(pj.x, fb[__float_as_int(pj.y)], o);     // 8 random j per instr
    }
    out[((size_t)batch * DFEAT + cc * 8 + c) * NPTS + i0 + row] = o;

    asm volatile("s_waitcnt vmcnt(0)" ::: "memory");
    __syncthreads();
  }
#undef STAGE
}

extern "C" void kernel_launch(void* const* d_in, const int* in_sizes, int n_in,
                              void* d_out, int out_size, void* d_ws, size_t ws_size,
                              hipStream_t stream) {
  const float* in = (const float*)d_in[0];
  float* out = (float*)d_out;
  float2* pairs = (float2*)d_ws;                           // 4 MB
  float*  rnjg  = (float*)((char*)d_ws + (16u << 20) / 4); // +4 MB: 64 KB table
  gnn_rnj<<<dim3(64), dim3(256), 0, stream>>>(in, rnjg);
  gnn_sim_topk<<<dim3(2048), dim3(256), 0, stream>>>(in, rnjg, pairs);
  gnn_gather<<<dim3(512), dim3(256), 0, stream>>>(in, pairs, out);
}

// Round 19
// 102.308 us; speedup vs baseline: 1.8100x; 1.1218x over previous
//
#include <hip/hip_runtime.h>
#include <math.h>

#define CT    320
#define NPTS  1024
#define DFEAT 256
#define DPOS  64
#define KSEL  32

// ============ Kernel C: per-point 1/max(||pos||,eps) -> rnjg (ws) ===========
__global__ void gnn_rnj(const float* __restrict__ in, float* __restrict__ rnjg) {
  const int b     = blockIdx.x;
  const int batch = b >> 2;
  const int j     = ((b & 3) << 8) + threadIdx.x;
  const float* __restrict__ pbase = in + (size_t)batch * CT * NPTS + (size_t)DFEAT * NPTS;
  float s = 0.f;
#pragma unroll 8
  for (int d = 0; d < DPOS; ++d) {
    const float x = pbase[(size_t)d * NPTS + j];
    s = fmaf(x, x, s);
  }
  rnjg[batch * NPTS + j] = 1.0f / fmaxf(sqrtf(s), 1e-12f);
}

// ================= Kernel A: round-11 config FROZEN (best: 64 us) ===========
// 1024 blocks; 16 rows/blk; wave owns 4 full rows; triple-buffered jt with
// counted vmcnt(2); 15-bit float-threshold exact top-32 + softmax.
#define AROWS 16
#define DCH   2
#define QSTEP 6.103515625e-05f          // 2^-14, thr(m) = m*QSTEP - 1 (exact)
__global__ __launch_bounds__(256, 4) void gnn_sim_topk(const float* __restrict__ in,
                                                       const float* __restrict__ rnjg,
                                                       float2* __restrict__ pairs) {
  __shared__ float pi[DPOS * 20];
  __shared__ float rnjL[NPTS];
  __shared__ float jt[3][DCH * 1024];
  __shared__ float cand[AROWS][68];

  const int p     = blockIdx.x;
  const int batch = ((p & 7) << 1) | ((p >> 3) & 1);
  const int chunk = p >> 4;
  const int i0    = chunk * AROWS;
  const int tid   = threadIdx.x;
  const int w     = tid >> 6;
  const int lane  = tid & 63;

  const float* __restrict__ pbase = in + (size_t)batch * CT * NPTS + (size_t)DFEAT * NPTS;

  {
    const int i = tid & 15;
    const int d0 = tid >> 4;
#pragma unroll
    for (int pass = 0; pass < 4; ++pass) {
      const int d = pass * 16 + d0;
      pi[d * 20 + i] = pbase[(size_t)d * NPTS + i0 + i];
    }
  }
  *(float4*)&rnjL[tid * 4] = *(const float4*)&rnjg[batch * NPTS + tid * 4];

#define JSTAGE(buf, c)                                                           \
  do {                                                                           \
    const int dd_   = (w >> 1);                                                  \
    const int half_ = (w & 1);                                                   \
    const float* src_ = pbase + (size_t)((c) * DCH + dd_) * NPTS + half_ * 512 + lane * 4; \
    float* dst_ = &jt[buf][dd_ * 1024 + half_ * 512];                            \
    __builtin_amdgcn_global_load_lds(                                            \
        (const __attribute__((address_space(1))) void*)(src_),                   \
        (__attribute__((address_space(3))) void*)(dst_), 16, 0, 0);              \
    __builtin_amdgcn_global_load_lds(                                            \
        (const __attribute__((address_space(1))) void*)(src_ + 256),             \
        (__attribute__((address_space(3))) void*)(dst_ + 256), 16, 0, 0);        \
  } while (0)

  JSTAGE(0, 0);
  JSTAGE(1, 1);
  asm volatile("s_waitcnt vmcnt(2)" ::: "memory");
  __syncthreads();

  float acc[4][16];
#pragma unroll
  for (int r = 0; r < 4; ++r)
#pragma unroll
    for (int s = 0; s < 16; ++s) acc[r][s] = 0.f;

  int cur = 0;
  for (int c = 0; c < DPOS / DCH; ++c) {
#pragma unroll
    for (int dd = 0; dd < DCH; ++dd) {
      const int d = c * DCH + dd;
      const float4 pv4 = *(const float4*)&pi[d * 20 + w * 4];
      const float pr_[4] = {pv4.x, pv4.y, pv4.z, pv4.w};
      float4 jv[4];
#pragma unroll
      for (int u = 0; u < 4; ++u)
        jv[u] = *(const float4*)&jt[cur][dd * 1024 + u * 256 + lane * 4];
#pragma unroll
      for (int r = 0; r < 4; ++r) {
#pragma unroll
        for (int u = 0; u < 4; ++u) {
          acc[r][u*4+0] = fmaf(pr_[r], jv[u].x, acc[r][u*4+0]);
          acc[r][u*4+1] = fmaf(pr_[r], jv[u].y, acc[r][u*4+1]);
          acc[r][u*4+2] = fmaf(pr_[r], jv[u].z, acc[r][u*4+2]);
          acc[r][u*4+3] = fmaf(pr_[r], jv[u].w, acc[r][u*4+3]);
        }
      }
    }
    if (c < DPOS / DCH - 2) {
      const int nbuf = (cur + 2 >= 3) ? cur - 1 : cur + 2;
      JSTAGE(nbuf, c + 2);
      asm volatile("s_waitcnt vmcnt(2)" ::: "memory");
    } else {
      asm volatile("s_waitcnt vmcnt(0)" ::: "memory");
    }
    __syncthreads();
    cur = (cur + 1 >= 3) ? 0 : cur + 1;
  }
#undef JSTAGE

  float4 rv[4];
#pragma unroll
  for (int u = 0; u < 4; ++u) rv[u] = *(const float4*)&rnjL[u * 256 + lane * 4];

#pragma unroll
  for (int r = 0; r < 4; ++r) {
    const int rglob = w * 4 + r;
    const float sc = rnjL[i0 + rglob];
    float v[16];
#pragma unroll
    for (int u = 0; u < 4; ++u) {
      v[u*4+0] = acc[r][u*4+0] * rv[u].x * sc;
      v[u*4+1] = acc[r][u*4+1] * rv[u].y * sc;
      v[u*4+2] = acc[r][u*4+2] * rv[u].z * sc;
      v[u*4+3] = acc[r][u*4+3] * rv[u].w * sc;
    }
    int lo = 0;
#pragma unroll
    for (int bit = 16384; bit >= 1; bit >>= 1) {
      const float thrf = (float)(lo + bit) * QSTEP - 1.0f;
      int cnt = 0;
#pragma unroll
      for (int t = 0; t < 16; ++t) cnt += (int)__popcll(__ballot(v[t] >= thrf));
      if (cnt >= KSEL) lo += bit;
    }
    const float thr_h = (float)(lo + 1) * QSTEP - 1.0f;
    const float thr_l = (float)lo * QSTEP - 1.0f;
    int cbase = 0;
    unsigned cmask = 0u;
#pragma unroll
    for (int t = 0; t < 16; ++t) {
      const bool hi = (v[t] >= thr_h);
      const unsigned long long m = __ballot(hi);
      if (hi) {
        const int pos = cbase + (int)__builtin_amdgcn_mbcnt_hi(
            (unsigned)(m >> 32), __builtin_amdgcn_mbcnt_lo((unsigned)m, 0u));
        const int j = (t >> 2) * 256 + lane * 4 + (t & 3);
        *(float2*)&cand[rglob][2 * pos] = make_float2(v[t], __int_as_float(j));
      }
      cbase += (int)__popcll(m);
      if ((v[t] >= thr_l) && !hi) cmask |= (1u << t);
    }
    const int need = KSEL - cbase;
    for (int it = 0; it < need; ++it) {
      float bv = -2.0f; int bj = 0x7fffffff; int bt = 16;
#pragma unroll
      for (int t = 0; t < 16; ++t) {
        if (((cmask >> t) & 1u) && v[t] > bv) {
          bv = v[t]; bj = (t >> 2) * 256 + lane * 4 + (t & 3); bt = t;
        }
      }
      float rvv = bv; int rj = bj;
#pragma unroll
      for (int s = 1; s < 64; s <<= 1) {
        const float ov = __shfl_xor(rvv, s);
        const int   oj = __shfl_xor(rj, s);
        if (ov > rvv || (ov == rvv && oj < rj)) { rvv = ov; rj = oj; }
      }
      if (bv == rvv && bj == rj) {
        *(float2*)&cand[rglob][2 * (cbase + it)] = make_float2(bv, __int_as_float(bj));
        cmask &= ~(1u << bt);
      }
    }
    {
      const float x = cand[rglob][2 * (lane & 31)];
      float mx = x;
#pragma unroll
      for (int s = 16; s >= 1; s >>= 1) mx = fmaxf(mx, __shfl_xor(mx, s));
      const float e = expf(x - mx);
      float sum = e;
#pragma unroll
      for (int s = 16; s >= 1; s >>= 1) sum += __shfl_xor(sum, s);
      if (lane < KSEL) cand[rglob][2 * lane] = e / sum;
    }
  }
  __syncthreads();

  {
    const int pidx = tid * 2;
    const int r = pidx >> 5, k = pidx & 31;
    const float4 o4 = *(const float4*)&cand[r][2 * k];
    *(float4*)&pairs[((size_t)batch * NPTS + i0 + r) * KSEL + k] = o4;
  }
}

// ================= Kernel B: wave-private, barrier-free gather (round-19) ===
// 512 blocks x 256 threads; block = 32 rows x 256 channels. Wave w stages ITS
// OWN 2 channel-rows/pass into ITS OWN LDS region (fst[w]) -> zero
// __syncthreads in the main loop; double-buffered, counted vmcnt(8). Pairs
// loaded into registers ONCE (a[32]/jj[32], static-indexed). 8 independent
// waves/CU hide each other's staging latency.
__global__ __launch_bounds__(256, 2) void gnn_gather(const float* __restrict__ in,
                                                     const float2* __restrict__ pairs,
                                                     float* __restrict__ out) {
  __shared__ float fst[4][2][2048];    // [wave][buf][2 channel-rows] = 64 KB

  const int p     = blockIdx.x;
  const int batch = ((p & 7) << 1) | ((p >> 3) & 1);   // 2 batches per XCD
  const int chunk = p >> 4;            // 0..31
  const int i0    = chunk * 32;
  const int tid   = threadIdx.x;
  const int w     = tid >> 6;
  const int lane  = tid & 63;
  const int row   = lane & 31;         // row within tile
  const int half  = lane >> 5;         // which of the wave's 2 channels

  const float* __restrict__ fbase = in + (size_t)batch * CT * NPTS;

  // this row's 32 (attn, id) pairs -> registers, once; id -> LDS float index
  float a[KSEL]; int jj[KSEL];
  {
    const float4* pr4 = (const float4*)(pairs + ((size_t)batch * NPTS + i0 + row) * KSEL);
#pragma unroll
    for (int q = 0; q < 16; ++q) {
      const float4 o4 = pr4[q];
      a[2*q]   = o4.x; jj[2*q]   = __float_as_int(o4.y) + half * 1024;
      a[2*q+1] = o4.z; jj[2*q+1] = __float_as_int(o4.w) + half * 1024;
    }
  }

  // wave w stages channels {cc*8 + 2w, cc*8 + 2w + 1} (8 x 16B-wide async)
#define BSTAGE(buf, ccv)                                                         \
  do {                                                                           \
    _Pragma("unroll")                                                            \
    for (int rr = 0; rr < 2; ++rr) {                                             \
      const int ch = (ccv) * 8 + w * 2 + rr;                                     \
      const float* src = fbase + (size_t)ch * NPTS + lane * 4;                   \
      float* dst = &fst[w][buf][rr * 1024];                                      \
      _Pragma("unroll")                                                          \
      for (int qq = 0; qq < 4; ++qq)                                             \
        __builtin_amdgcn_global_load_lds(                                        \
            (const __attribute__((address_space(1))) void*)(src + qq * 256),     \
            (__attribute__((address_space(3))) void*)(dst + qq * 256), 16, 0, 0);\
    }                                                                            \
  } while (0)

  BSTAGE(0, 0);
  int cur = 0;
  for (int cc = 0; cc < 32; ++cc) {
    if (cc < 31) {
      BSTAGE(cur ^ 1, cc + 1);                         // issue next pass early
      asm volatile("s_waitcnt vmcnt(8)" ::: "memory"); // current pass landed
    } else {
      asm volatile("s_waitcnt vmcnt(0)" ::: "memory");
    }
    const float* fb = &fst[w][cur][0];
    float o = 0.f;
#pragma unroll
    for (int k = 0; k < KSEL; ++k)     // k ascending: bitwise-same sum order
      o = fmaf(a[k], fb[jj[k]], o);
    const int ch = cc * 8 + w * 2 + half;
    out[((size_t)batch * DFEAT + ch) * NPTS + i0 + row] = o;
    cur ^= 1;
  }
#undef BSTAGE
}

extern "C" void kernel_launch(void* const* d_in, const int* in_sizes, int n_in,
                              void* d_out, int out_size, void* d_ws, size_t ws_size,
                              hipStream_t stream) {
  const float* in = (const float*)d_in[0];
  float* out = (float*)d_out;
  float2* pairs = (float2*)d_ws;                           // 4 MB
  float*  rnjg  = (float*)((char*)d_ws + (16u << 20) / 4); // +4 MB: 64 KB table
  gnn_rnj<<<dim3(64), dim3(256), 0, stream>>>(in, rnjg);
  gnn_sim_topk<<<dim3(1024), dim3(256), 0, stream>>>(in, rnjg, pairs);
  gnn_gather<<<dim3(512), dim3(256), 0, stream>>>(in, pairs, out);
}

// Round 20
// 99.021 us; speedup vs baseline: 1.8700x; 1.0332x over previous
//
#include <hip/hip_runtime.h>
#include <math.h>

#define CT    320
#define NPTS  1024
#define DFEAT 256
#define DPOS  64
#define KSEL  32

// ============ Kernel C: per-point 1/max(||pos||,eps) -> rnjg (ws) ===========
__global__ void gnn_rnj(const float* __restrict__ in, float* __restrict__ rnjg) {
  const int b     = blockIdx.x;
  const int batch = b >> 2;
  const int j     = ((b & 3) << 8) + threadIdx.x;
  const float* __restrict__ pbase = in + (size_t)batch * CT * NPTS + (size_t)DFEAT * NPTS;
  float s = 0.f;
#pragma unroll 8
  for (int d = 0; d < DPOS; ++d) {
    const float x = pbase[(size_t)d * NPTS + j];
    s = fmaf(x, x, s);
  }
  rnjg[batch * NPTS + j] = 1.0f / fmaxf(sqrtf(s), 1e-12f);
}

// ================= Kernel A: round-11 config FROZEN (best: 64 us) ===========
#define AROWS 16
#define DCH   2
#define QSTEP 6.103515625e-05f          // 2^-14, thr(m) = m*QSTEP - 1 (exact)
__global__ __launch_bounds__(256, 4) void gnn_sim_topk(const float* __restrict__ in,
                                                       const float* __restrict__ rnjg,
                                                       float2* __restrict__ pairs) {
  __shared__ float pi[DPOS * 20];
  __shared__ float rnjL[NPTS];
  __shared__ float jt[3][DCH * 1024];
  __shared__ float cand[AROWS][68];

  const int p     = blockIdx.x;
  const int batch = ((p & 7) << 1) | ((p >> 3) & 1);
  const int chunk = p >> 4;
  const int i0    = chunk * AROWS;
  const int tid   = threadIdx.x;
  const int w     = tid >> 6;
  const int lane  = tid & 63;

  const float* __restrict__ pbase = in + (size_t)batch * CT * NPTS + (size_t)DFEAT * NPTS;

  {
    const int i = tid & 15;
    const int d0 = tid >> 4;
#pragma unroll
    for (int pass = 0; pass < 4; ++pass) {
      const int d = pass * 16 + d0;
      pi[d * 20 + i] = pbase[(size_t)d * NPTS + i0 + i];
    }
  }
  *(float4*)&rnjL[tid * 4] = *(const float4*)&rnjg[batch * NPTS + tid * 4];

#define JSTAGE(buf, c)                                                           \
  do {                                                                           \
    const int dd_   = (w >> 1);                                                  \
    const int half_ = (w & 1);                                                   \
    const float* src_ = pbase + (size_t)((c) * DCH + dd_) * NPTS + half_ * 512 + lane * 4; \
    float* dst_ = &jt[buf][dd_ * 1024 + half_ * 512];                            \
    __builtin_amdgcn_global_load_lds(                                            \
        (const __attribute__((address_space(1))) void*)(src_),                   \
        (__attribute__((address_space(3))) void*)(dst_), 16, 0, 0);              \
    __builtin_amdgcn_global_load_lds(                                            \
        (const __attribute__((address_space(1))) void*)(src_ + 256),             \
        (__attribute__((address_space(3))) void*)(dst_ + 256), 16, 0, 0);        \
  } while (0)

  JSTAGE(0, 0);
  JSTAGE(1, 1);
  asm volatile("s_waitcnt vmcnt(2)" ::: "memory");
  __syncthreads();

  float acc[4][16];
#pragma unroll
  for (int r = 0; r < 4; ++r)
#pragma unroll
    for (int s = 0; s < 16; ++s) acc[r][s] = 0.f;

  int cur = 0;
  for (int c = 0; c < DPOS / DCH; ++c) {
#pragma unroll
    for (int dd = 0; dd < DCH; ++dd) {
      const int d = c * DCH + dd;
      const float4 pv4 = *(const float4*)&pi[d * 20 + w * 4];
      const float pr_[4] = {pv4.x, pv4.y, pv4.z, pv4.w};
      float4 jv[4];
#pragma unroll
      for (int u = 0; u < 4; ++u)
        jv[u] = *(const float4*)&jt[cur][dd * 1024 + u * 256 + lane * 4];
#pragma unroll
      for (int r = 0; r < 4; ++r) {
#pragma unroll
        for (int u = 0; u < 4; ++u) {
          acc[r][u*4+0] = fmaf(pr_[r], jv[u].x, acc[r][u*4+0]);
          acc[r][u*4+1] = fmaf(pr_[r], jv[u].y, acc[r][u*4+1]);
          acc[r][u*4+2] = fmaf(pr_[r], jv[u].z, acc[r][u*4+2]);
          acc[r][u*4+3] = fmaf(pr_[r], jv[u].w, acc[r][u*4+3]);
        }
      }
    }
    if (c < DPOS / DCH - 2) {
      const int nbuf = (cur + 2 >= 3) ? cur - 1 : cur + 2;
      JSTAGE(nbuf, c + 2);
      asm volatile("s_waitcnt vmcnt(2)" ::: "memory");
    } else {
      asm volatile("s_waitcnt vmcnt(0)" ::: "memory");
    }
    __syncthreads();
    cur = (cur + 1 >= 3) ? 0 : cur + 1;
  }
#undef JSTAGE

  float4 rv[4];
#pragma unroll
  for (int u = 0; u < 4; ++u) rv[u] = *(const float4*)&rnjL[u * 256 + lane * 4];

#pragma unroll
  for (int r = 0; r < 4; ++r) {
    const int rglob = w * 4 + r;
    const float sc = rnjL[i0 + rglob];
    float v[16];
#pragma unroll
    for (int u = 0; u < 4; ++u) {
      v[u*4+0] = acc[r][u*4+0] * rv[u].x * sc;
      v[u*4+1] = acc[r][u*4+1] * rv[u].y * sc;
      v[u*4+2] = acc[r][u*4+2] * rv[u].z * sc;
      v[u*4+3] = acc[r][u*4+3] * rv[u].w * sc;
    }
    int lo = 0;
#pragma unroll
    for (int bit = 16384; bit >= 1; bit >>= 1) {
      const float thrf = (float)(lo + bit) * QSTEP - 1.0f;
      int cnt = 0;
#pragma unroll
      for (int t = 0; t < 16; ++t) cnt += (int)__popcll(__ballot(v[t] >= thrf));
      if (cnt >= KSEL) lo += bit;
    }
    const float thr_h = (float)(lo + 1) * QSTEP - 1.0f;
    const float thr_l = (float)lo * QSTEP - 1.0f;
    int cbase = 0;
    unsigned cmask = 0u;
#pragma unroll
    for (int t = 0; t < 16; ++t) {
      const bool hi = (v[t] >= thr_h);
      const unsigned long long m = __ballot(hi);
      if (hi) {
        const int pos = cbase + (int)__builtin_amdgcn_mbcnt_hi(
            (unsigned)(m >> 32), __builtin_amdgcn_mbcnt_lo((unsigned)m, 0u));
        const int j = (t >> 2) * 256 + lane * 4 + (t & 3);
        *(float2*)&cand[rglob][2 * pos] = make_float2(v[t], __int_as_float(j));
      }
      cbase += (int)__popcll(m);
      if ((v[t] >= thr_l) && !hi) cmask |= (1u << t);
    }
    const int need = KSEL - cbase;
    for (int it = 0; it < need; ++it) {
      float bv = -2.0f; int bj = 0x7fffffff; int bt = 16;
#pragma unroll
      for (int t = 0; t < 16; ++t) {
        if (((cmask >> t) & 1u) && v[t] > bv) {
          bv = v[t]; bj = (t >> 2) * 256 + lane * 4 + (t & 3); bt = t;
        }
      }
      float rvv = bv; int rj = bj;
#pragma unroll
      for (int s = 1; s < 64; s <<= 1) {
        const float ov = __shfl_xor(rvv, s);
        const int   oj = __shfl_xor(rj, s);
        if (ov > rvv || (ov == rvv && oj < rj)) { rvv = ov; rj = oj; }
      }
      if (bv == rvv && bj == rj) {
        *(float2*)&cand[rglob][2 * (cbase + it)] = make_float2(bv, __int_as_float(bj));
        cmask &= ~(1u << bt);
      }
    }
    {
      const float x = cand[rglob][2 * (lane & 31)];
      float mx = x;
#pragma unroll
      for (int s = 16; s >= 1; s >>= 1) mx = fmaxf(mx, __shfl_xor(mx, s));
      const float e = expf(x - mx);
      float sum = e;
#pragma unroll
      for (int s = 16; s >= 1; s >>= 1) sum += __shfl_xor(sum, s);
      if (lane < KSEL) cand[rglob][2 * lane] = e / sum;
    }
  }
  __syncthreads();

  {
    const int pidx = tid * 2;
    const int r = pidx >> 5, k = pidx & 31;
    const float4 o4 = *(const float4*)&cand[r][2 * k];
    *(float4*)&pairs[((size_t)batch * NPTS + i0 + r) * KSEL + k] = o4;
  }
}

// ====== Kernel B: transposed-LDS float4 gather, wave-private (round-20) =====
// 512 blocks x 256 threads; wave w owns channels [w*64, w*64+64) x 32 rows,
// 16 passes of 4 channels. Staged tile is TRANSPOSED: LDS granule
// G(j) = ((j&3)<<6)|((j>>2)&63)|(j&~255) holds float4 {ch0..ch3}[j].
//  - writes: lane's coalesced float4 loads at j=256*it+4*lane map to granules
//    256*it+64*q+lane  -> stride-1 in lane -> conflict-free 8-cyc writes.
//  - reads: one ds_read_b128 at random G(j) serves 4 channels (4x fewer
//    gather instrs than scalar); random granules are bank-balanced.
// k split across half-waves (lane=row+32*khalf), shfl_xor(32) combine.
// Zero barriers; single buffer/wave; T14 issue-early loads hide under gather.
__global__ __launch_bounds__(256, 2) void gnn_gather(const float* __restrict__ in,
                                                     const float2* __restrict__ pairs,
                                                     float* __restrict__ out) {
  __shared__ float fst[4][4096];       // per-wave 16 KB: 1024 granules x 16B

  const int p     = blockIdx.x;
  const int batch = ((p & 7) << 1) | ((p >> 3) & 1);   // 2 batches per XCD
  const int chunk = p >> 4;            // 0..31
  const int i0    = chunk * 32;
  const int tid   = threadIdx.x;
  const int w     = tid >> 6;
  const int lane  = tid & 63;
  const int row   = lane & 31;
  const int khalf = lane >> 5;         // 0: k 0..15, 1: k 16..31
  const int ch0   = w * 64;            // wave's channel range

  const float* __restrict__ fbase = in + (size_t)batch * CT * NPTS;
  float* const fw = &fst[w][0];

  // this lane's 16 (attn, byte-offset) pairs (its k-half), swizzled offsets
  float a16[16]; int jjb[16];
  {
    const float4* pr4 = (const float4*)(pairs + ((size_t)batch * NPTS + i0 + row) * KSEL)
                        + khalf * 8;
#pragma unroll
    for (int qq = 0; qq < 8; ++qq) {
      const float4 o = pr4[qq];
      const int id0 = __float_as_int(o.y);
      const int id1 = __float_as_int(o.w);
      a16[2*qq]   = o.x;
      jjb[2*qq]   = ((((id0 & 3) << 6) | ((id0 >> 2) & 63) | (id0 & ~255)) << 4);
      a16[2*qq+1] = o.z;
      jjb[2*qq+1] = ((((id1 & 3) << 6) | ((id1 >> 2) & 63) | (id1 & ~255)) << 4);
    }
  }

  float4 tile[4][4];                   // [it][c], all indices compile-time

#define LOADT(pp)                                                                \
  do {                                                                           \
    _Pragma("unroll")                                                            \
    for (int it = 0; it < 4; ++it) {                                             \
      _Pragma("unroll")                                                          \
      for (int c = 0; c < 4; ++c)                                                \
        tile[it][c] = *(const float4*)(fbase +                                   \
            (size_t)(ch0 + (pp) * 4 + c) * NPTS + it * 256 + lane * 4);          \
    }                                                                            \
  } while (0)

#define WRITET()                                                                 \
  do {                                                                           \
    _Pragma("unroll")                                                            \
    for (int it = 0; it < 4; ++it) {                                             \
      *(float4*)&fw[(256*it + lane) * 4] =                                       \
          make_float4(tile[it][0].x, tile[it][1].x, tile[it][2].x, tile[it][3].x);\
      *(float4*)&fw[(256*it + 64 + lane) * 4] =                                  \
          make_float4(tile[it][0].y, tile[it][1].y, tile[it][2].y, tile[it][3].y);\
      *(float4*)&fw[(256*it + 128 + lane) * 4] =                                 \
          make_float4(tile[it][0].z, tile[it][1].z, tile[it][2].z, tile[it][3].z);\
      *(float4*)&fw[(256*it + 192 + lane) * 4] =                                 \
          make_float4(tile[it][0].w, tile[it][1].w, tile[it][2].w, tile[it][3].w);\
    }                                                                            \
  } while (0)

  LOADT(0);
  WRITET();                            // compiler waits loads before first use

  for (int pp = 0; pp < 16; ++pp) {
    if (pp < 15) LOADT(pp + 1);        // issue next tile early (T14)

    // gather pass pp: 16 x ds_read_b128, each feeds 4 channels
    float4 o4 = make_float4(0.f, 0.f, 0.f, 0.f);
#pragma unroll
    for (int kk = 0; kk < 16; ++kk) {
      const float4 f4 = *(const float4*)((const char*)fw + jjb[kk]);
      const float ak = a16[kk];
      o4.x = fmaf(ak, f4.x, o4.x);
      o4.y = fmaf(ak, f4.y, o4.y);
      o4.z = fmaf(ak, f4.z, o4.z);
      o4.w = fmaf(ak, f4.w, o4.w);
    }
    // combine k-halves across the wave (lane <-> lane+32, same row)
    o4.x += __shfl_xor(o4.x, 32);
    o4.y += __shfl_xor(o4.y, 32);
    o4.z += __shfl_xor(o4.z, 32);
    o4.w += __shfl_xor(o4.w, 32);

    float* ob = out + ((size_t)batch * DFEAT + ch0 + pp * 4) * NPTS + i0 + row;
    if (khalf == 0) {
      ob[0]            = o4.x;
      ob[(size_t)NPTS] = o4.y;
    } else {
      ob[(size_t)2 * NPTS] = o4.z;
      ob[(size_t)3 * NPTS] = o4.w;
    }

    if (pp < 15) WRITET();             // LDS write after gather reads (in-order DS)
  }
#undef LOADT
#undef WRITET
}

extern "C" void kernel_launch(void* const* d_in, const int* in_sizes, int n_in,
                              void* d_out, int out_size, void* d_ws, size_t ws_size,
                              hipStream_t stream) {
  const float* in = (const float*)d_in[0];
  float* out = (float*)d_out;
  float2* pairs = (float2*)d_ws;                           // 4 MB
  float*  rnjg  = (float*)((char*)d_ws + (16u << 20) / 4); // +4 MB: 64 KB table
  gnn_rnj<<<dim3(64), dim3(256), 0, stream>>>(in, rnjg);
  gnn_sim_topk<<<dim3(1024), dim3(256), 0, stream>>>(in, rnjg, pairs);
  gnn_gather<<<dim3(512), dim3(256), 0, stream>>>(in, pairs, out);
}